// Round 1
// baseline (4678.591 us; speedup 1.0000x reference)
//
#include <hip/hip_runtime.h>
#include <math.h>

#define DIMC 1024
#define SEQ  2048
#define BATCH 4
#define NTOK (BATCH * SEQ)   // 8192
#define HEADS 16
#define HD   64

// ---------------------------------------------------------------------------
// Tiled fp32 GEMM: C[M,N] = act(A[M,K] @ B + bias)
//   BT=false: Bm is [K,N] row-major (w / wo layout: [in, out])
//   BT=true : Bm is [N,K] row-major (pw layout: [out, in])
// 64x64 tile, Ktile=64, 256 threads, 4x4 accum per thread.
// ---------------------------------------------------------------------------
template<bool BT, bool SILU>
__global__ __launch_bounds__(256)
void gemm_f32(const float* __restrict__ A, const float* __restrict__ Bm,
              const float* __restrict__ bias, float* __restrict__ C,
              int M, int N, int K)
{
    __shared__ float As[64][65];  // [m][k]
    __shared__ float Bs[64][65];  // [k][n]
    const int tid = threadIdx.x;
    const int tx = tid & 15, ty = tid >> 4;
    const int m0 = blockIdx.y * 64, n0 = blockIdx.x * 64;

    float acc[4][4] = {};

    for (int k0 = 0; k0 < K; k0 += 64) {
#pragma unroll
        for (int i = 0; i < 16; ++i) {
            int l = tid + i * 256;
            int r = l >> 6, c = l & 63;
            As[r][c] = A[(size_t)(m0 + r) * K + (k0 + c)];
            if (!BT) {
                Bs[r][c] = Bm[(size_t)(k0 + r) * N + (n0 + c)];
            } else {
                Bs[c][r] = Bm[(size_t)(n0 + r) * K + (k0 + c)];
            }
        }
        __syncthreads();
#pragma unroll 8
        for (int k = 0; k < 64; ++k) {
            float a[4], bb[4];
#pragma unroll
            for (int i = 0; i < 4; ++i) a[i] = As[4 * ty + i][k];
#pragma unroll
            for (int j = 0; j < 4; ++j) bb[j] = Bs[k][4 * tx + j];
#pragma unroll
            for (int i = 0; i < 4; ++i)
#pragma unroll
                for (int j = 0; j < 4; ++j)
                    acc[i][j] = fmaf(a[i], bb[j], acc[i][j]);
        }
        __syncthreads();
    }

#pragma unroll
    for (int i = 0; i < 4; ++i)
#pragma unroll
        for (int j = 0; j < 4; ++j) {
            float v = acc[i][j] + bias[n0 + 4 * tx + j];
            if (SILU) v = v * (1.0f / (1.0f + expf(-v)));
            C[(size_t)(m0 + 4 * ty + i) * N + (n0 + 4 * tx + j)] = v;
        }
}

// ---------------------------------------------------------------------------
// Depthwise conv k=3 pad=1 over seq (per channel) + bias.
// X, Y: [B, S, C] flattened. dw: [C,1,3], dwb: [C].
// ---------------------------------------------------------------------------
__global__ __launch_bounds__(256)
void dwconv_k3(const float* __restrict__ X, const float* __restrict__ dw,
               const float* __restrict__ dwb, float* __restrict__ Y)
{
    int idx = blockIdx.x * 256 + threadIdx.x;          // element index
    int c = idx & (DIMC - 1);
    int t = idx >> 10;                                 // token index
    int s = t & (SEQ - 1);
    float w0 = dw[c * 3 + 0], w1 = dw[c * 3 + 1], w2 = dw[c * 3 + 2];
    float xm = (s > 0)       ? X[idx - DIMC] : 0.0f;
    float xc = X[idx];
    float xp = (s < SEQ - 1) ? X[idx + DIMC] : 0.0f;
    Y[idx] = fmaf(w0, xm, fmaf(w1, xc, fmaf(w2, xp, dwb[c])));
}

// ---------------------------------------------------------------------------
// In-place row L2 normalize over DIMC. One block per row.
// ---------------------------------------------------------------------------
__global__ __launch_bounds__(256)
void l2norm_rows(float* __restrict__ X)
{
    float* p = X + (size_t)blockIdx.x * DIMC;
    float s = 0.0f;
    for (int i = threadIdx.x; i < DIMC; i += 256) { float v = p[i]; s += v * v; }
#pragma unroll
    for (int off = 32; off; off >>= 1) s += __shfl_down(s, off, 64);
    __shared__ float part[4];
    if ((threadIdx.x & 63) == 0) part[threadIdx.x >> 6] = s;
    __syncthreads();
    float tot = part[0] + part[1] + part[2] + part[3];
    float inv = 1.0f / fmaxf(sqrtf(tot), 1e-12f);
    for (int i = threadIdx.x; i < DIMC; i += 256) p[i] *= inv;
}

// ---------------------------------------------------------------------------
// Flash-style fp32 attention. One block per (q-tile of 64, b*h).
// Q,K,V: [B,S,DIMC] with head h occupying cols [h*64, h*64+64).
// O: [B,S,DIMC] same layout. mask: [B,S] int (0 -> masked out key).
// ---------------------------------------------------------------------------
__global__ __launch_bounds__(256)
void flash_attn_f32(const float* __restrict__ Q, const float* __restrict__ Km,
                    const float* __restrict__ V, const int* __restrict__ mask,
                    float* __restrict__ O)
{
    __shared__ float Qs[64][65], Ks[64][65], Vs[64][65], Ps[64][65];
    __shared__ float red[64][17];
    const int tid = threadIdx.x;
    const int tx = tid & 15, ty = tid >> 4;
    const int qt = blockIdx.x;            // 0..31
    const int bh = blockIdx.y;            // 0..63
    const int b = bh >> 4, h = bh & 15;
    const size_t base = (size_t)b * SEQ * DIMC + (size_t)h * HD;

#pragma unroll
    for (int i = 0; i < 16; ++i) {
        int l = tid + i * 256; int r = l >> 6, c = l & 63;
        Qs[r][c] = Q[base + (size_t)(qt * 64 + r) * DIMC + c];
    }
    float m_i[4], l_i[4], o_acc[4][4] = {};
#pragma unroll
    for (int i = 0; i < 4; ++i) { m_i[i] = -1e30f; l_i[i] = 0.0f; }
    __syncthreads();

    for (int kt = 0; kt < 32; ++kt) {
#pragma unroll
        for (int i = 0; i < 16; ++i) {
            int l = tid + i * 256; int r = l >> 6, c = l & 63;
            size_t g = base + (size_t)(kt * 64 + r) * DIMC + c;
            Ks[r][c] = Km[g];
            Vs[r][c] = V[g];
        }
        __syncthreads();

        // S tile = Q K^T
        float sacc[4][4] = {};
#pragma unroll 8
        for (int d = 0; d < 64; ++d) {
            float a[4], bb[4];
#pragma unroll
            for (int i = 0; i < 4; ++i) a[i] = Qs[4 * ty + i][d];
#pragma unroll
            for (int j = 0; j < 4; ++j) bb[j] = Ks[4 * tx + j][d];
#pragma unroll
            for (int i = 0; i < 4; ++i)
#pragma unroll
                for (int j = 0; j < 4; ++j)
                    sacc[i][j] = fmaf(a[i], bb[j], sacc[i][j]);
        }
        // scale + mask
        float s_ij[4][4];
        const int mbase = b * SEQ + kt * 64 + 4 * tx;
#pragma unroll
        for (int j = 0; j < 4; ++j) {
            bool ok = mask[mbase + j] != 0;
#pragma unroll
            for (int i = 0; i < 4; ++i)
                s_ij[i][j] = ok ? sacc[i][j] * 0.125f : -1e30f;
        }
        // row max across tx
#pragma unroll
        for (int i = 0; i < 4; ++i) {
            float tm = fmaxf(fmaxf(s_ij[i][0], s_ij[i][1]), fmaxf(s_ij[i][2], s_ij[i][3]));
            red[4 * ty + i][tx] = tm;
        }
        __syncthreads();
        float mnew[4], alpha[4];
#pragma unroll
        for (int i = 0; i < 4; ++i) {
            float tm = m_i[i];
#pragma unroll
            for (int t = 0; t < 16; ++t) tm = fmaxf(tm, red[4 * ty + i][t]);
            mnew[i] = tm;
            alpha[i] = expf(m_i[i] - tm);
        }
        float p[4][4], psum[4];
#pragma unroll
        for (int i = 0; i < 4; ++i) {
            psum[i] = 0.0f;
#pragma unroll
            for (int j = 0; j < 4; ++j) { p[i][j] = expf(s_ij[i][j] - mnew[i]); psum[i] += p[i][j]; }
        }
        __syncthreads();  // red reuse
#pragma unroll
        for (int i = 0; i < 4; ++i) {
            red[4 * ty + i][tx] = psum[i];
#pragma unroll
            for (int j = 0; j < 4; ++j) Ps[4 * ty + i][4 * tx + j] = p[i][j];
        }
        __syncthreads();
#pragma unroll
        for (int i = 0; i < 4; ++i) {
            float ls = 0.0f;
#pragma unroll
            for (int t = 0; t < 16; ++t) ls += red[4 * ty + i][t];
            l_i[i] = alpha[i] * l_i[i] + ls;
            m_i[i] = mnew[i];
#pragma unroll
            for (int j = 0; j < 4; ++j) o_acc[i][j] *= alpha[i];
        }
        // O += P V
#pragma unroll 8
        for (int c = 0; c < 64; ++c) {
            float pv[4], vv[4];
#pragma unroll
            for (int i = 0; i < 4; ++i) pv[i] = Ps[4 * ty + i][c];
#pragma unroll
            for (int j = 0; j < 4; ++j) vv[j] = Vs[c][4 * tx + j];
#pragma unroll
            for (int i = 0; i < 4; ++i)
#pragma unroll
                for (int j = 0; j < 4; ++j)
                    o_acc[i][j] = fmaf(pv[i], vv[j], o_acc[i][j]);
        }
        __syncthreads();  // protect Ks/Vs/Ps before next tile load
    }

#pragma unroll
    for (int i = 0; i < 4; ++i) {
        float invl = 1.0f / l_i[i];
#pragma unroll
        for (int j = 0; j < 4; ++j) {
            size_t orow = (size_t)(b * SEQ + qt * 64 + 4 * ty + i) * DIMC
                        + (size_t)h * HD + 4 * tx + j;
            O[orow] = o_acc[i][j] * invl;
        }
    }
}

// ---------------------------------------------------------------------------
extern "C" void kernel_launch(void* const* d_in, const int* in_sizes, int n_in,
                              void* d_out, int out_size, void* d_ws, size_t ws_size,
                              hipStream_t stream)
{
    const float* x    = (const float*)d_in[0];
    const int*   mask = (const int*)  d_in[1];
    const float* wq   = (const float*)d_in[2];
    const float* bq   = (const float*)d_in[3];
    const float* dwq  = (const float*)d_in[4];
    const float* dwbq = (const float*)d_in[5];
    const float* pwq  = (const float*)d_in[6];
    const float* pwbq = (const float*)d_in[7];
    const float* wk   = (const float*)d_in[8];
    const float* bk   = (const float*)d_in[9];
    const float* dwk  = (const float*)d_in[10];
    const float* dwbk = (const float*)d_in[11];
    const float* pwk  = (const float*)d_in[12];
    const float* pwbk = (const float*)d_in[13];
    const float* wv   = (const float*)d_in[14];
    const float* bv   = (const float*)d_in[15];
    const float* dwv  = (const float*)d_in[16];
    const float* dwbv = (const float*)d_in[17];
    const float* pwv  = (const float*)d_in[18];
    const float* pwbv = (const float*)d_in[19];
    const float* wo   = (const float*)d_in[20];
    const float* bo   = (const float*)d_in[21];

    float* out = (float*)d_out;
    const size_t NE = (size_t)NTOK * DIMC;  // 8.39M elements
    float* qb = (float*)d_ws;
    float* kb = qb + NE;
    float* vb = kb + NE;
    float* tb = vb + NE;     // depthwise scratch / attention output

    const dim3 gemm_grid(DIMC / 64, NTOK / 64);   // (16, 128)
    const dim3 attn_grid(SEQ / 64, BATCH * HEADS); // (32, 64)
    const int elem_blocks = (int)(NE / 256);

    // q/k/v = silu(x @ w + b)
    gemm_f32<false, true><<<gemm_grid, 256, 0, stream>>>(x, wq, bq, qb, NTOK, DIMC, DIMC);
    gemm_f32<false, true><<<gemm_grid, 256, 0, stream>>>(x, wk, bk, kb, NTOK, DIMC, DIMC);
    gemm_f32<false, true><<<gemm_grid, 256, 0, stream>>>(x, wv, bv, vb, NTOK, DIMC, DIMC);

    // ds_conv per tensor: depthwise(k=3) -> tb, then pointwise GEMM back in place
    dwconv_k3<<<elem_blocks, 256, 0, stream>>>(qb, dwq, dwbq, tb);
    gemm_f32<true, false><<<gemm_grid, 256, 0, stream>>>(tb, pwq, pwbq, qb, NTOK, DIMC, DIMC);
    dwconv_k3<<<elem_blocks, 256, 0, stream>>>(kb, dwk, dwbk, tb);
    gemm_f32<true, false><<<gemm_grid, 256, 0, stream>>>(tb, pwk, pwbk, kb, NTOK, DIMC, DIMC);
    dwconv_k3<<<elem_blocks, 256, 0, stream>>>(vb, dwv, dwbv, tb);
    gemm_f32<true, false><<<gemm_grid, 256, 0, stream>>>(tb, pwv, pwbv, vb, NTOK, DIMC, DIMC);

    // l2 normalize q, k over full dim
    l2norm_rows<<<NTOK, 256, 0, stream>>>(qb);
    l2norm_rows<<<NTOK, 256, 0, stream>>>(kb);

    // attention -> tb
    flash_attn_f32<<<attn_grid, 256, 0, stream>>>(qb, kb, vb, mask, tb);

    // final projection
    gemm_f32<false, false><<<gemm_grid, 256, 0, stream>>>(tb, wo, bo, out, NTOK, DIMC, DIMC);
}

// Round 2
// 777.368 us; speedup vs baseline: 6.0185x; 6.0185x over previous
//
#include <hip/hip_runtime.h>
#include <math.h>

#define DIMC 1024
#define SEQ  2048
#define BATCH 4
#define NTOK 8192
#define HEADS 16
#define HD 64

typedef __attribute__((ext_vector_type(8))) short short8;
typedef __attribute__((ext_vector_type(4))) float f32x4;

#define GLDS(gp, lp) __builtin_amdgcn_global_load_lds(                        \
    (const __attribute__((address_space(1))) void*)(gp),                      \
    (__attribute__((address_space(3))) void*)(lp), 16, 0, 0)

__device__ __forceinline__ float bf2f(unsigned short u) {
    union { unsigned int i; float f; } v; v.i = ((unsigned int)u) << 16; return v.f;
}
__device__ __forceinline__ unsigned short f2bf(float f) {
    union { float f; unsigned int i; } v; v.f = f;
    unsigned int r = v.i + 0x7FFFu + ((v.i >> 16) & 1u);
    return (unsigned short)(r >> 16);
}

// ---------------------------------------------------------------------------
// fp32 -> bf16 convert (flat)
// ---------------------------------------------------------------------------
__global__ __launch_bounds__(256)
void cvt_f32_bf16(const float* __restrict__ X, unsigned short* __restrict__ Y, int n)
{
    int i = blockIdx.x * 256 + threadIdx.x;
    if (i < n) Y[i] = f2bf(X[i]);
}

// ---------------------------------------------------------------------------
// W [in=1024][out=1024] fp32 -> Wt [out][in] bf16 (transpose + convert)
// ---------------------------------------------------------------------------
__global__ __launch_bounds__(256)
void transpose_cvt(const float* __restrict__ W, unsigned short* __restrict__ Wt)
{
    __shared__ float T[32][33];
    int i0 = blockIdx.y * 32, o0 = blockIdx.x * 32;
    int c = threadIdx.x & 31, r4 = threadIdx.x >> 5;
#pragma unroll
    for (int p = 0; p < 4; ++p) {
        int r = r4 + p * 8;
        T[r][c] = W[(size_t)(i0 + r) * DIMC + o0 + c];
    }
    __syncthreads();
#pragma unroll
    for (int p = 0; p < 4; ++p) {
        int r = r4 + p * 8;
        Wt[(size_t)(o0 + r) * DIMC + i0 + c] = f2bf(T[c][r]);
    }
}

// ---------------------------------------------------------------------------
// bf16 MFMA GEMM: C[M,N] = act(A[M,K] @ Bt^T + bias)
// A: [M][K] bf16 row-major; Bt: [N][K] bf16 row-major (pre-transposed weight).
// 128x128 tile, BK=32, 256 threads = 4 waves (2x2), each wave 64x64 via 4x4
// MFMA 16x16x32 tiles. global_load_lds width-16 staging (m97 structure).
// ---------------------------------------------------------------------------
template<bool SILU, bool F32OUT>
__global__ __launch_bounds__(256)
void gemm_mfma(const unsigned short* __restrict__ A,
               const unsigned short* __restrict__ Bt,
               const float* __restrict__ bias,
               void* __restrict__ Cout, int M, int N, int K)
{
    __shared__ unsigned short As[128 * 32];
    __shared__ unsigned short Bs[128 * 32];
    const int tid = threadIdx.x;
    const int lane = tid & 63;
    const int quad = lane >> 4, l16 = lane & 15;
    const int wave = tid >> 6;
    const int wm = (wave & 1) * 64, wn = (wave >> 1) * 64;
    const int m0 = blockIdx.y * 128, n0 = blockIdx.x * 128;

    f32x4 acc[4][4];
#pragma unroll
    for (int i = 0; i < 4; ++i)
#pragma unroll
        for (int j = 0; j < 4; ++j) acc[i][j] = (f32x4)(0.0f);

    for (int k0 = 0; k0 < K; k0 += 32) {
#pragma unroll
        for (int t = 0; t < 2; ++t) {
            int o = (t * 256 + tid) * 8;          // bf16-element offset, 16B per lane
            int row = o >> 5, col = o & 31;
            GLDS(A  + (size_t)(m0 + row) * K + k0 + col, As + o);
            GLDS(Bt + (size_t)(n0 + row) * K + k0 + col, Bs + o);
        }
        __syncthreads();
        short8 af[4], bfb[4];
#pragma unroll
        for (int i = 0; i < 4; ++i)
            af[i] = *(const short8*)(As + (wm + i * 16 + l16) * 32 + quad * 8);
#pragma unroll
        for (int j = 0; j < 4; ++j)
            bfb[j] = *(const short8*)(Bs + (wn + j * 16 + l16) * 32 + quad * 8);
#pragma unroll
        for (int i = 0; i < 4; ++i)
#pragma unroll
            for (int j = 0; j < 4; ++j)
                acc[i][j] = __builtin_amdgcn_mfma_f32_16x16x32_bf16(af[i], bfb[j], acc[i][j], 0, 0, 0);
        __syncthreads();
    }

#pragma unroll
    for (int i = 0; i < 4; ++i) {
        int mrow = m0 + wm + i * 16 + quad * 4;   // + r
#pragma unroll
        for (int j = 0; j < 4; ++j) {
            int ncol = n0 + wn + j * 16 + l16;
            float bval = bias[ncol];
#pragma unroll
            for (int r = 0; r < 4; ++r) {
                float v = acc[i][j][r] + bval;
                if (SILU) v = v / (1.0f + __expf(-v));
                if (F32OUT)
                    ((float*)Cout)[(size_t)(mrow + r) * N + ncol] = v;
                else
                    ((unsigned short*)Cout)[(size_t)(mrow + r) * N + ncol] = f2bf(v);
            }
        }
    }
}

// ---------------------------------------------------------------------------
// Depthwise conv k=3 pad=1 over seq + bias (bf16 in/out, fp32 math)
// ---------------------------------------------------------------------------
__global__ __launch_bounds__(256)
void dwconv_bf16(const unsigned short* __restrict__ X, const float* __restrict__ dw,
                 const float* __restrict__ dwb, unsigned short* __restrict__ Y)
{
    int idx = blockIdx.x * 256 + threadIdx.x;
    int c = idx & (DIMC - 1);
    int s = (idx >> 10) & (SEQ - 1);
    float w0 = dw[c * 3 + 0], w1 = dw[c * 3 + 1], w2 = dw[c * 3 + 2];
    float xm = (s > 0)       ? bf2f(X[idx - DIMC]) : 0.0f;
    float xc = bf2f(X[idx]);
    float xp = (s < SEQ - 1) ? bf2f(X[idx + DIMC]) : 0.0f;
    Y[idx] = f2bf(fmaf(w0, xm, fmaf(w1, xc, fmaf(w2, xp, dwb[c]))));
}

// ---------------------------------------------------------------------------
// In-place row L2 normalize (bf16, fp32 accumulate). One block per row.
// ---------------------------------------------------------------------------
__global__ __launch_bounds__(256)
void l2norm_bf16(unsigned short* __restrict__ X)
{
    unsigned short* p = X + (size_t)blockIdx.x * DIMC;
    float s = 0.0f;
    for (int i = threadIdx.x; i < DIMC; i += 256) { float v = bf2f(p[i]); s += v * v; }
#pragma unroll
    for (int off = 32; off; off >>= 1) s += __shfl_down(s, off, 64);
    __shared__ float part[4];
    if ((threadIdx.x & 63) == 0) part[threadIdx.x >> 6] = s;
    __syncthreads();
    float tot = part[0] + part[1] + part[2] + part[3];
    float inv = 1.0f / fmaxf(sqrtf(tot), 1e-12f);
    for (int i = threadIdx.x; i < DIMC; i += 256) p[i] = f2bf(bf2f(p[i]) * inv);
}

// ---------------------------------------------------------------------------
// V [B,S,C] bf16 -> Vt [B*H][64][SEQ] bf16 (per-head transpose)
// ---------------------------------------------------------------------------
__global__ __launch_bounds__(256)
void vtrans(const unsigned short* __restrict__ V, unsigned short* __restrict__ Vt)
{
    __shared__ unsigned short T[64][65];
    int st = blockIdx.x, bh = blockIdx.y;
    int b = bh >> 4, h = bh & 15;
    int tid = threadIdx.x;
#pragma unroll
    for (int t = 0; t < 16; ++t) {
        int o = t * 256 + tid; int r = o >> 6, c = o & 63;
        T[r][c] = V[(size_t)(b * SEQ + st * 64 + r) * DIMC + h * HD + c];
    }
    __syncthreads();
#pragma unroll
    for (int t = 0; t < 16; ++t) {
        int o = t * 256 + tid; int r = o >> 6, c = o & 63;
        Vt[(size_t)bh * HD * SEQ + (size_t)r * SEQ + st * 64 + c] = T[c][r];
    }
}

// ---------------------------------------------------------------------------
// Flash attention, bf16 MFMA. Grid (SEQ/64, B*H), 256 threads = 4 waves.
// Each wave owns 16 q-rows. Q,K: [B,S,C]; Vt: [B*H][64][SEQ]; O: [B,S,C].
// ---------------------------------------------------------------------------
__global__ __launch_bounds__(256)
void attn_mfma(const unsigned short* __restrict__ Q,
               const unsigned short* __restrict__ Km,
               const unsigned short* __restrict__ Vt,
               const int* __restrict__ mask,
               unsigned short* __restrict__ O)
{
    __shared__ unsigned short Qs[64 * 64], Ks[64 * 64], Vs[64 * 64];
    __shared__ unsigned short Ps[4][16 * 64];
    const int tid = threadIdx.x, lane = tid & 63, wave = tid >> 6;
    const int quad = lane >> 4, l16 = lane & 15;
    const int qt = blockIdx.x, bh = blockIdx.y;
    const int b = bh >> 4, h = bh & 15;
    const size_t qkbase = (size_t)b * SEQ * DIMC + (size_t)h * HD;
    const size_t vtbase = (size_t)bh * HD * SEQ;

    // stage Q tile [64 q][64 d], LDS rows of 64 bf16
#pragma unroll
    for (int t = 0; t < 2; ++t) {
        int o = (t * 256 + tid) * 8;
        int row = o >> 6, col = o & 63;
        GLDS(Q + qkbase + (size_t)(qt * 64 + row) * DIMC + col, Qs + o);
    }

    f32x4 oacc[4];
#pragma unroll
    for (int t = 0; t < 4; ++t) oacc[t] = (f32x4)(0.0f);
    float m_i[4], l_i[4];
#pragma unroll
    for (int r = 0; r < 4; ++r) { m_i[r] = -1e30f; l_i[r] = 0.0f; }

    for (int kt = 0; kt < SEQ / 64; ++kt) {
#pragma unroll
        for (int t = 0; t < 2; ++t) {
            int o = (t * 256 + tid) * 8;
            int row = o >> 6, col = o & 63;
            GLDS(Km + qkbase + (size_t)(kt * 64 + row) * DIMC + col, Ks + o);
            GLDS(Vt + vtbase + (size_t)row * SEQ + kt * 64 + col,   Vs + o);
        }
        __syncthreads();

        // S = Q K^T  (wave's 16 q-rows x 64 k-cols)
        f32x4 sacc[4];
#pragma unroll
        for (int t = 0; t < 4; ++t) sacc[t] = (f32x4)(0.0f);
        short8 aq0 = *(const short8*)(Qs + (wave * 16 + l16) * 64 + quad * 8);
        short8 aq1 = *(const short8*)(Qs + (wave * 16 + l16) * 64 + 32 + quad * 8);
#pragma unroll
        for (int t = 0; t < 4; ++t) {
            short8 bk0 = *(const short8*)(Ks + (t * 16 + l16) * 64 + quad * 8);
            short8 bk1 = *(const short8*)(Ks + (t * 16 + l16) * 64 + 32 + quad * 8);
            sacc[t] = __builtin_amdgcn_mfma_f32_16x16x32_bf16(aq0, bk0, sacc[t], 0, 0, 0);
            sacc[t] = __builtin_amdgcn_mfma_f32_16x16x32_bf16(aq1, bk1, sacc[t], 0, 0, 0);
        }

        // scale + mask; online softmax over this lane's cols, rows quad*4+r
        float sv[4][4];   // [t][r]
        const int kbase = b * SEQ + kt * 64;
#pragma unroll
        for (int t = 0; t < 4; ++t) {
            bool ok = mask[kbase + t * 16 + l16] != 0;
#pragma unroll
            for (int r = 0; r < 4; ++r)
                sv[t][r] = ok ? sacc[t][r] * 0.125f : -1e30f;
        }
        float p[4][4];
#pragma unroll
        for (int r = 0; r < 4; ++r) {
            float mx = fmaxf(fmaxf(sv[0][r], sv[1][r]), fmaxf(sv[2][r], sv[3][r]));
#pragma unroll
            for (int off = 1; off < 16; off <<= 1) mx = fmaxf(mx, __shfl_xor(mx, off, 64));
            float mnew = fmaxf(m_i[r], mx);
            float alpha = __expf(m_i[r] - mnew);
            float s = 0.0f;
#pragma unroll
            for (int t = 0; t < 4; ++t) { float e = __expf(sv[t][r] - mnew); p[t][r] = e; s += e; }
#pragma unroll
            for (int off = 1; off < 16; off <<= 1) s += __shfl_xor(s, off, 64);
            l_i[r] = alpha * l_i[r] + s;
            m_i[r] = mnew;
#pragma unroll
            for (int t = 0; t < 4; ++t) oacc[t][r] *= alpha;
        }

        // P: C-layout -> LDS (per-wave region) -> A-layout
        unsigned short* Pw = Ps[wave];
#pragma unroll
        for (int r = 0; r < 4; ++r)
#pragma unroll
            for (int t = 0; t < 4; ++t)
                Pw[(quad * 4 + r) * 64 + t * 16 + l16] = f2bf(p[t][r]);
        // same-wave LDS RAW: ds ops in-order per wave; no barrier needed.

        short8 ap0 = *(const short8*)(Pw + l16 * 64 + quad * 8);
        short8 ap1 = *(const short8*)(Pw + l16 * 64 + 32 + quad * 8);
#pragma unroll
        for (int t = 0; t < 4; ++t) {
            short8 bv0 = *(const short8*)(Vs + (t * 16 + l16) * 64 + quad * 8);
            short8 bv1 = *(const short8*)(Vs + (t * 16 + l16) * 64 + 32 + quad * 8);
            oacc[t] = __builtin_amdgcn_mfma_f32_16x16x32_bf16(ap0, bv0, oacc[t], 0, 0, 0);
            oacc[t] = __builtin_amdgcn_mfma_f32_16x16x32_bf16(ap1, bv1, oacc[t], 0, 0, 0);
        }
        __syncthreads();   // protect Ks/Vs before next tile's staging
    }

#pragma unroll
    for (int r = 0; r < 4; ++r) {
        float inv = 1.0f / l_i[r];
        int grow = qt * 64 + wave * 16 + quad * 4 + r;
#pragma unroll
        for (int t = 0; t < 4; ++t)
            O[(size_t)(b * SEQ + grow) * DIMC + h * HD + t * 16 + l16] =
                f2bf(oacc[t][r] * inv);
    }
}

// ---------------------------------------------------------------------------
extern "C" void kernel_launch(void* const* d_in, const int* in_sizes, int n_in,
                              void* d_out, int out_size, void* d_ws, size_t ws_size,
                              hipStream_t stream)
{
    const float* x    = (const float*)d_in[0];
    const int*   mask = (const int*)  d_in[1];
    const float* wq   = (const float*)d_in[2];
    const float* bq   = (const float*)d_in[3];
    const float* dwq  = (const float*)d_in[4];
    const float* dwbq = (const float*)d_in[5];
    const float* pwq  = (const float*)d_in[6];
    const float* pwbq = (const float*)d_in[7];
    const float* wk   = (const float*)d_in[8];
    const float* bk   = (const float*)d_in[9];
    const float* dwk  = (const float*)d_in[10];
    const float* dwbk = (const float*)d_in[11];
    const float* pwk  = (const float*)d_in[12];
    const float* pwbk = (const float*)d_in[13];
    const float* wv   = (const float*)d_in[14];
    const float* bv   = (const float*)d_in[15];
    const float* dwv  = (const float*)d_in[16];
    const float* dwbv = (const float*)d_in[17];
    const float* pwv  = (const float*)d_in[18];
    const float* pwbv = (const float*)d_in[19];
    const float* wo   = (const float*)d_in[20];
    const float* bo   = (const float*)d_in[21];

    float* out = (float*)d_out;
    const size_t NE = (size_t)NTOK * DIMC;      // 8.39M
    const size_t WE = (size_t)DIMC * DIMC;      // 1.05M
    unsigned short* xb  = (unsigned short*)d_ws;
    unsigned short* qb  = xb + NE;
    unsigned short* kb  = qb + NE;
    unsigned short* vb  = kb + NE;
    unsigned short* tb  = vb + NE;
    unsigned short* vt  = tb + NE;
    unsigned short* ob  = vt + NE;
    unsigned short* wtq = ob + NE;
    unsigned short* wtk = wtq + WE;
    unsigned short* wtv = wtk + WE;
    unsigned short* wto = wtv + WE;
    unsigned short* pq  = wto + WE;
    unsigned short* pk  = pq + WE;
    unsigned short* pv  = pk + WE;

    const dim3 tgrid(32, 32);
    const dim3 ggrid(DIMC / 128, NTOK / 128);   // (8, 64)
    const dim3 agrid(SEQ / 64, BATCH * HEADS);  // (32, 64)
    const int eblk = (int)(NE / 256);
    const int wblk = (int)(WE / 256);

    // converts
    cvt_f32_bf16<<<eblk, 256, 0, stream>>>(x, xb, (int)NE);
    transpose_cvt<<<tgrid, 256, 0, stream>>>(wq, wtq);
    transpose_cvt<<<tgrid, 256, 0, stream>>>(wk, wtk);
    transpose_cvt<<<tgrid, 256, 0, stream>>>(wv, wtv);
    transpose_cvt<<<tgrid, 256, 0, stream>>>(wo, wto);
    cvt_f32_bf16<<<wblk, 256, 0, stream>>>(pwq, pq, (int)WE);
    cvt_f32_bf16<<<wblk, 256, 0, stream>>>(pwk, pk, (int)WE);
    cvt_f32_bf16<<<wblk, 256, 0, stream>>>(pwv, pv, (int)WE);

    // q/k/v = silu(x @ w + b)
    gemm_mfma<true, false><<<ggrid, 256, 0, stream>>>(xb, wtq, bq, qb, NTOK, DIMC, DIMC);
    gemm_mfma<true, false><<<ggrid, 256, 0, stream>>>(xb, wtk, bk, kb, NTOK, DIMC, DIMC);
    gemm_mfma<true, false><<<ggrid, 256, 0, stream>>>(xb, wtv, bv, vb, NTOK, DIMC, DIMC);

    // ds_conv: depthwise -> tb, pointwise GEMM back
    dwconv_bf16<<<eblk, 256, 0, stream>>>(qb, dwq, dwbq, tb);
    gemm_mfma<false, false><<<ggrid, 256, 0, stream>>>(tb, pq, pwbq, qb, NTOK, DIMC, DIMC);
    dwconv_bf16<<<eblk, 256, 0, stream>>>(kb, dwk, dwbk, tb);
    gemm_mfma<false, false><<<ggrid, 256, 0, stream>>>(tb, pk, pwbk, kb, NTOK, DIMC, DIMC);
    dwconv_bf16<<<eblk, 256, 0, stream>>>(vb, dwv, dwbv, tb);
    gemm_mfma<false, false><<<ggrid, 256, 0, stream>>>(tb, pv, pwbv, vb, NTOK, DIMC, DIMC);

    // l2 norm q, k
    l2norm_bf16<<<NTOK, 256, 0, stream>>>(qb);
    l2norm_bf16<<<NTOK, 256, 0, stream>>>(kb);

    // V transpose for PV B-fragments
    vtrans<<<agrid, 256, 0, stream>>>(vb, vt);

    // attention
    attn_mfma<<<agrid, 256, 0, stream>>>(qb, kb, vt, mask, ob);

    // final projection -> fp32 out
    gemm_mfma<false, true><<<ggrid, 256, 0, stream>>>(ob, wto, bo, out, NTOK, DIMC, DIMC);
}

// Round 3
// 574.762 us; speedup vs baseline: 8.1401x; 1.3525x over previous
//
#include <hip/hip_runtime.h>
#include <math.h>

#define DIMC 1024
#define SEQ  2048
#define BATCH 4
#define NTOK 8192
#define HEADS 16
#define HD 64

typedef __attribute__((ext_vector_type(8))) short short8;
typedef __attribute__((ext_vector_type(4))) float f32x4;

#define GLDS(gp, lp) __builtin_amdgcn_global_load_lds(                        \
    (const __attribute__((address_space(1))) void*)(gp),                      \
    (__attribute__((address_space(3))) void*)(lp), 16, 0, 0)

__device__ __forceinline__ float bf2f(unsigned short u) {
    union { unsigned int i; float f; } v; v.i = ((unsigned int)u) << 16; return v.f;
}
__device__ __forceinline__ unsigned short f2bf(float f) {
    union { float f; unsigned int i; } v; v.f = f;
    unsigned int r = v.i + 0x7FFFu + ((v.i >> 16) & 1u);
    return (unsigned short)(r >> 16);
}
// pack 2 floats -> 2 bf16 (round-half-up; p~1.0, bias negligible)
__device__ __forceinline__ unsigned int pk2bf(float a, float b) {
    union { float f; unsigned int u; } ua, ub; ua.f = a; ub.f = b;
    return ((ua.u + 0x8000u) >> 16) | ((ub.u + 0x8000u) & 0xFFFF0000u);
}

// ---------------------------------------------------------------------------
__global__ __launch_bounds__(256)
void cvt_f32_bf16(const float* __restrict__ X, unsigned short* __restrict__ Y, int n)
{
    int i = blockIdx.x * 256 + threadIdx.x;
    if (i < n) Y[i] = f2bf(X[i]);
}

// batched fp32->bf16 for the 3 pointwise weights
__global__ __launch_bounds__(256)
void cvt3(const float* __restrict__ A0, const float* __restrict__ A1,
          const float* __restrict__ A2,
          unsigned short* __restrict__ B0, unsigned short* __restrict__ B1,
          unsigned short* __restrict__ B2)
{
    int z = blockIdx.y;
    const float* X = z == 0 ? A0 : z == 1 ? A1 : A2;
    unsigned short* Y = z == 0 ? B0 : z == 1 ? B1 : B2;
    int i = blockIdx.x * 256 + threadIdx.x;
    Y[i] = f2bf(X[i]);
}

// mask -> additive float bias
__global__ __launch_bounds__(256)
void maskbias(const int* __restrict__ mask, float* __restrict__ fb)
{
    int i = blockIdx.x * 256 + threadIdx.x;
    fb[i] = (mask[i] != 0) ? 0.0f : -1e30f;
}

// ---------------------------------------------------------------------------
// W [in][out] fp32 -> Wt [out][in] bf16, batched over 4 weights (z)
// ---------------------------------------------------------------------------
__global__ __launch_bounds__(256)
void transpose_cvt4(const float* __restrict__ W0, const float* __restrict__ W1,
                    const float* __restrict__ W2, const float* __restrict__ W3,
                    unsigned short* __restrict__ T0, unsigned short* __restrict__ T1,
                    unsigned short* __restrict__ T2, unsigned short* __restrict__ T3)
{
    int z = blockIdx.z;
    const float* W = z == 0 ? W0 : z == 1 ? W1 : z == 2 ? W2 : W3;
    unsigned short* Wt = z == 0 ? T0 : z == 1 ? T1 : z == 2 ? T2 : T3;
    __shared__ float T[32][33];
    int i0 = blockIdx.y * 32, o0 = blockIdx.x * 32;
    int c = threadIdx.x & 31, r4 = threadIdx.x >> 5;
#pragma unroll
    for (int p = 0; p < 4; ++p) {
        int r = r4 + p * 8;
        T[r][c] = W[(size_t)(i0 + r) * DIMC + o0 + c];
    }
    __syncthreads();
#pragma unroll
    for (int p = 0; p < 4; ++p) {
        int r = r4 + p * 8;
        Wt[(size_t)(o0 + r) * DIMC + i0 + c] = f2bf(T[c][r]);
    }
}

// ---------------------------------------------------------------------------
// bf16 MFMA GEMM core (m97 structure): C = act(A @ Bt^T + bias)
// A:[M=NTOK][K=1024], Bt:[N=1024][K], 128x128 tile, BK=32, 4 waves.
// ---------------------------------------------------------------------------
template<bool SILU, bool F32OUT>
__device__ __forceinline__
void gemm_core(const unsigned short* __restrict__ A,
               const unsigned short* __restrict__ Bt,
               const float* __restrict__ bias, void* __restrict__ Cout)
{
    __shared__ unsigned short As[128 * 32];
    __shared__ unsigned short Bs[128 * 32];
    const int tid = threadIdx.x;
    const int lane = tid & 63;
    const int quad = lane >> 4, l16 = lane & 15;
    const int wave = tid >> 6;
    const int wm = (wave & 1) * 64, wn = (wave >> 1) * 64;
    const int m0 = blockIdx.y * 128, n0 = blockIdx.x * 128;
    const int K = DIMC, N = DIMC;

    f32x4 acc[4][4];
#pragma unroll
    for (int i = 0; i < 4; ++i)
#pragma unroll
        for (int j = 0; j < 4; ++j) acc[i][j] = (f32x4)(0.0f);

    for (int k0 = 0; k0 < K; k0 += 32) {
#pragma unroll
        for (int t = 0; t < 2; ++t) {
            int o = (t * 256 + tid) * 8;
            int row = o >> 5, col = o & 31;
            GLDS(A  + (size_t)(m0 + row) * K + k0 + col, As + o);
            GLDS(Bt + (size_t)(n0 + row) * K + k0 + col, Bs + o);
        }
        __syncthreads();
        short8 af[4], bfb[4];
#pragma unroll
        for (int i = 0; i < 4; ++i)
            af[i] = *(const short8*)(As + (wm + i * 16 + l16) * 32 + quad * 8);
#pragma unroll
        for (int j = 0; j < 4; ++j)
            bfb[j] = *(const short8*)(Bs + (wn + j * 16 + l16) * 32 + quad * 8);
#pragma unroll
        for (int i = 0; i < 4; ++i)
#pragma unroll
            for (int j = 0; j < 4; ++j)
                acc[i][j] = __builtin_amdgcn_mfma_f32_16x16x32_bf16(af[i], bfb[j], acc[i][j], 0, 0, 0);
        __syncthreads();
    }

#pragma unroll
    for (int i = 0; i < 4; ++i) {
        int mrow = m0 + wm + i * 16 + quad * 4;
#pragma unroll
        for (int j = 0; j < 4; ++j) {
            int ncol = n0 + wn + j * 16 + l16;
            float bval = bias[ncol];
#pragma unroll
            for (int r = 0; r < 4; ++r) {
                float v = acc[i][j][r] + bval;
                if (SILU) v = v / (1.0f + __expf(-v));
                if (F32OUT)
                    ((float*)Cout)[(size_t)(mrow + r) * N + ncol] = v;
                else
                    ((unsigned short*)Cout)[(size_t)(mrow + r) * N + ncol] = f2bf(v);
            }
        }
    }
}

__global__ __launch_bounds__(256)
void gemm_qkv(const unsigned short* A,
              const unsigned short* B0, const unsigned short* B1, const unsigned short* B2,
              const float* b0, const float* b1, const float* b2,
              unsigned short* C0, unsigned short* C1, unsigned short* C2)
{
    int z = blockIdx.z;
    gemm_core<true, false>(A, z == 0 ? B0 : z == 1 ? B1 : B2,
                           z == 0 ? b0 : z == 1 ? b1 : b2,
                           z == 0 ? C0 : z == 1 ? C1 : C2);
}

__global__ __launch_bounds__(256)
void gemm_pw(const unsigned short* A0, const unsigned short* A1, const unsigned short* A2,
             const unsigned short* B0, const unsigned short* B1, const unsigned short* B2,
             const float* b0, const float* b1, const float* b2,
             unsigned short* C0, unsigned short* C1, unsigned short* C2)
{
    int z = blockIdx.z;
    gemm_core<false, false>(z == 0 ? A0 : z == 1 ? A1 : A2,
                            z == 0 ? B0 : z == 1 ? B1 : B2,
                            z == 0 ? b0 : z == 1 ? b1 : b2,
                            z == 0 ? C0 : z == 1 ? C1 : C2);
}

__global__ __launch_bounds__(256)
void gemm_wo(const unsigned short* A, const unsigned short* Bt,
             const float* bias, float* C)
{
    gemm_core<false, true>(A, Bt, bias, C);
}

// ---------------------------------------------------------------------------
// Depthwise conv k=3 pad=1 over seq + bias, batched over q/k/v (blockIdx.y)
// ---------------------------------------------------------------------------
__global__ __launch_bounds__(256)
void dwconv3(const unsigned short* __restrict__ qb, const unsigned short* __restrict__ kb,
             const unsigned short* __restrict__ vb,
             const float* __restrict__ dwq, const float* __restrict__ dwbq,
             const float* __restrict__ dwk, const float* __restrict__ dwbk,
             const float* __restrict__ dwv, const float* __restrict__ dwbv,
             unsigned short* __restrict__ o0, unsigned short* __restrict__ o1,
             unsigned short* __restrict__ o2)
{
    int z = blockIdx.y;
    const unsigned short* X = z == 0 ? qb : z == 1 ? kb : vb;
    const float* dw  = z == 0 ? dwq  : z == 1 ? dwk  : dwv;
    const float* dwb = z == 0 ? dwbq : z == 1 ? dwbk : dwbv;
    unsigned short* Y = z == 0 ? o0 : z == 1 ? o1 : o2;

    int idx = blockIdx.x * 256 + threadIdx.x;
    int c = idx & (DIMC - 1);
    int s = (idx >> 10) & (SEQ - 1);
    float w0 = dw[c * 3 + 0], w1 = dw[c * 3 + 1], w2 = dw[c * 3 + 2];
    float xm = (s > 0)       ? bf2f(X[idx - DIMC]) : 0.0f;
    float xc = bf2f(X[idx]);
    float xp = (s < SEQ - 1) ? bf2f(X[idx + DIMC]) : 0.0f;
    Y[idx] = f2bf(fmaf(w0, xm, fmaf(w1, xc, fmaf(w2, xp, dwb[c]))));
}

// ---------------------------------------------------------------------------
// Row L2 normalize, batched (y=0: q with folded softmax scale, y=1: k).
// post-scale folds 1/sqrt(HD) * log2(e) into q for exp2-domain softmax.
// ---------------------------------------------------------------------------
__global__ __launch_bounds__(256)
void l2norm2(unsigned short* __restrict__ Xq, unsigned short* __restrict__ Xk)
{
    unsigned short* X = blockIdx.y ? Xk : Xq;
    const float post = blockIdx.y ? 1.0f : 0.125f * 1.44269504088896f;
    unsigned short* p = X + (size_t)blockIdx.x * DIMC;
    ushort4 v = ((ushort4*)p)[threadIdx.x];
    float f0 = bf2f(v.x), f1 = bf2f(v.y), f2 = bf2f(v.z), f3 = bf2f(v.w);
    float s = f0 * f0 + f1 * f1 + f2 * f2 + f3 * f3;
#pragma unroll
    for (int off = 32; off; off >>= 1) s += __shfl_down(s, off, 64);
    __shared__ float part[4];
    if ((threadIdx.x & 63) == 0) part[threadIdx.x >> 6] = s;
    __syncthreads();
    float tot = part[0] + part[1] + part[2] + part[3];
    float inv = post / fmaxf(sqrtf(tot), 1e-12f);
    v.x = f2bf(f0 * inv); v.y = f2bf(f1 * inv);
    v.z = f2bf(f2 * inv); v.w = f2bf(f3 * inv);
    ((ushort4*)p)[threadIdx.x] = v;
}

// ---------------------------------------------------------------------------
// V [B,S,C] bf16 -> Vt [B*H][64][SEQ] bf16 (per-head transpose)
// ---------------------------------------------------------------------------
__global__ __launch_bounds__(256)
void vtrans(const unsigned short* __restrict__ V, unsigned short* __restrict__ Vt)
{
    __shared__ unsigned short T[64][65];
    int st = blockIdx.x, bh = blockIdx.y;
    int b = bh >> 4, h = bh & 15;
    int tid = threadIdx.x;
#pragma unroll
    for (int t = 0; t < 16; ++t) {
        int o = t * 256 + tid; int r = o >> 6, c = o & 63;
        T[r][c] = V[(size_t)(b * SEQ + st * 64 + r) * DIMC + h * HD + c];
    }
    __syncthreads();
#pragma unroll
    for (int t = 0; t < 16; ++t) {
        int o = t * 256 + tid; int r = o >> 6, c = o & 63;
        Vt[(size_t)bh * HD * SEQ + (size_t)r * SEQ + st * 64 + c] = T[c][r];
    }
}

// ---------------------------------------------------------------------------
// Flash attention v2: no-max softmax (scores bounded by l2norm; scale folded
// into q), S^T MFMA (A=K, B=Q) so P packs as b64 writes, XOR-swizzled LDS,
// Q frags in registers. Grid (SEQ/128, B*H), 256 thr = 4 waves, 32 q/wave.
// ---------------------------------------------------------------------------
__global__ __launch_bounds__(256, 2)
void attn_mfma2(const unsigned short* __restrict__ Q,
                const unsigned short* __restrict__ Km,
                const unsigned short* __restrict__ Vt,
                const float* __restrict__ fbias,
                unsigned short* __restrict__ O)
{
    __shared__ unsigned short Ks[64 * 64];      // [k][d], chunk-swizzled
    __shared__ unsigned short Vs[64 * 64];      // [d][k], chunk-swizzled
    __shared__ unsigned short Ps[4][32 * 64];   // per-wave [q][k], swizzled
    const int tid = threadIdx.x, lane = tid & 63, wave = tid >> 6;
    const int quad = lane >> 4, l16 = lane & 15;
    const int qt = blockIdx.x, bh = blockIdx.y;
    const int b = bh >> 4, h = bh & 15;
    const size_t qkbase = (size_t)b * SEQ * DIMC + (size_t)h * HD;
    const size_t vtbase = (size_t)bh * HD * SEQ;
    const int qbaseW = qt * 128 + wave * 32;

    // Q B-fragments: loop-invariant, straight from global.
    short8 aq[2][2];
#pragma unroll
    for (int sub = 0; sub < 2; ++sub)
#pragma unroll
        for (int hf = 0; hf < 2; ++hf)
            aq[sub][hf] = *(const short8*)(Q + qkbase +
                (size_t)(qbaseW + sub * 16 + l16) * DIMC + hf * 32 + quad * 8);

    f32x4 oacc[2][4];
#pragma unroll
    for (int s = 0; s < 2; ++s)
#pragma unroll
        for (int t = 0; t < 4; ++t) oacc[s][t] = (f32x4)(0.0f);
    float lsum[2] = {0.0f, 0.0f};

    unsigned short* Pw = Ps[wave];

    for (int kt = 0; kt < SEQ / 64; ++kt) {
        __syncthreads();   // prior tile's reads done before overwrite
#pragma unroll
        for (int t = 0; t < 2; ++t) {
            int s = t * 256 + tid;         // 16B-chunk slot
            int srow = s >> 3, sc = s & 7;
            int lc = sc ^ (srow & 7);      // swizzle: choose global chunk
            GLDS(Km + qkbase + (size_t)(kt * 64 + srow) * DIMC + lc * 8, Ks + s * 8);
            GLDS(Vt + vtbase + (size_t)srow * SEQ + kt * 64 + lc * 8,   Vs + s * 8);
        }
        __syncthreads();

        // K A-frags + V B-frags (swizzled reads, ~conflict-free)
        short8 ak0[4], ak1[4], bv0[4], bv1[4];
#pragma unroll
        for (int t = 0; t < 4; ++t) {
            int row = t * 16 + l16, sw = row & 7;
            ak0[t] = *(const short8*)(Ks + row * 64 + ((quad ^ sw) * 8));
            ak1[t] = *(const short8*)(Ks + row * 64 + (((4 + quad) ^ sw) * 8));
            bv0[t] = *(const short8*)(Vs + row * 64 + ((quad ^ sw) * 8));
            bv1[t] = *(const short8*)(Vs + row * 64 + (((4 + quad) ^ sw) * 8));
        }

#pragma unroll
        for (int sub = 0; sub < 2; ++sub) {
            // S^T tiles: rows k (t*16+quad*4+r), cols q (l16)
            f32x4 sacc[4];
#pragma unroll
            for (int t = 0; t < 4; ++t) sacc[t] = (f32x4)(0.0f);
#pragma unroll
            for (int t = 0; t < 4; ++t) {
                sacc[t] = __builtin_amdgcn_mfma_f32_16x16x32_bf16(ak0[t], aq[sub][0], sacc[t], 0, 0, 0);
                sacc[t] = __builtin_amdgcn_mfma_f32_16x16x32_bf16(ak1[t], aq[sub][1], sacc[t], 0, 0, 0);
            }
            const int prow = sub * 16 + l16;
            const int psw = prow & 7;
            float ls = 0.0f;
#pragma unroll
            for (int t = 0; t < 4; ++t) {
                float4 fb = *(const float4*)(fbias + (size_t)b * SEQ + kt * 64 + t * 16 + quad * 4);
                float p0 = exp2f(sacc[t][0] + fb.x);
                float p1 = exp2f(sacc[t][1] + fb.y);
                float p2 = exp2f(sacc[t][2] + fb.z);
                float p3 = exp2f(sacc[t][3] + fb.w);
                ls += (p0 + p1) + (p2 + p3);
                uint2 w; w.x = pk2bf(p0, p1); w.y = pk2bf(p2, p3);
                int chunk = (t * 2 + (quad >> 1)) ^ psw;
                *(uint2*)(Pw + prow * 64 + chunk * 8 + (quad & 1) * 4) = w;
            }
            lsum[sub] += ls;
        }

        // PV: O[q][d] += P[q][k] @ V^T  (A=P from LDS, B=Vt frags)
#pragma unroll
        for (int sub = 0; sub < 2; ++sub) {
            const int prow = sub * 16 + l16;
            const int psw = prow & 7;
            short8 ap0 = *(const short8*)(Pw + prow * 64 + ((quad ^ psw) * 8));
            short8 ap1 = *(const short8*)(Pw + prow * 64 + (((4 + quad) ^ psw) * 8));
#pragma unroll
            for (int t = 0; t < 4; ++t) {
                oacc[sub][t] = __builtin_amdgcn_mfma_f32_16x16x32_bf16(ap0, bv0[t], oacc[sub][t], 0, 0, 0);
                oacc[sub][t] = __builtin_amdgcn_mfma_f32_16x16x32_bf16(ap1, bv1[t], oacc[sub][t], 0, 0, 0);
            }
        }
    }

    // epilogue: finish l (reduce over quads; each lane's l16 is its q), write O
#pragma unroll
    for (int sub = 0; sub < 2; ++sub) {
        float l = lsum[sub];
        l += __shfl_xor(l, 16, 64);
        l += __shfl_xor(l, 32, 64);
#pragma unroll
        for (int r = 0; r < 4; ++r) {
            float lr = __shfl(l, (lane & 48) | (quad * 4 + r), 64);
            float inv = 1.0f / lr;
            int grow = qbaseW + sub * 16 + quad * 4 + r;
#pragma unroll
            for (int t = 0; t < 4; ++t)
                O[(size_t)(b * SEQ + grow) * DIMC + h * HD + t * 16 + l16] =
                    f2bf(oacc[sub][t][r] * inv);
        }
    }
}

// ---------------------------------------------------------------------------
extern "C" void kernel_launch(void* const* d_in, const int* in_sizes, int n_in,
                              void* d_out, int out_size, void* d_ws, size_t ws_size,
                              hipStream_t stream)
{
    const float* x    = (const float*)d_in[0];
    const int*   mask = (const int*)  d_in[1];
    const float* wq   = (const float*)d_in[2];
    const float* bq   = (const float*)d_in[3];
    const float* dwq  = (const float*)d_in[4];
    const float* dwbq = (const float*)d_in[5];
    const float* pwq  = (const float*)d_in[6];
    const float* pwbq = (const float*)d_in[7];
    const float* wk   = (const float*)d_in[8];
    const float* bk   = (const float*)d_in[9];
    const float* dwk  = (const float*)d_in[10];
    const float* dwbk = (const float*)d_in[11];
    const float* pwk  = (const float*)d_in[12];
    const float* pwbk = (const float*)d_in[13];
    const float* wv   = (const float*)d_in[14];
    const float* bv   = (const float*)d_in[15];
    const float* dwv  = (const float*)d_in[16];
    const float* dwbv = (const float*)d_in[17];
    const float* pwv  = (const float*)d_in[18];
    const float* pwbv = (const float*)d_in[19];
    const float* wo   = (const float*)d_in[20];
    const float* bo   = (const float*)d_in[21];

    float* out = (float*)d_out;
    const size_t NE = (size_t)NTOK * DIMC;
    const size_t WE = (size_t)DIMC * DIMC;
    unsigned short* xb  = (unsigned short*)d_ws;   // x bf16; later dwconv-q out; later attn out
    unsigned short* qb  = xb + NE;
    unsigned short* kb  = qb + NE;
    unsigned short* vb  = kb + NE;
    unsigned short* tbA = vb + NE;
    unsigned short* tbB = tbA + NE;
    unsigned short* vt  = tbB + NE;
    unsigned short* wtq = vt + NE;
    unsigned short* wtk = wtq + WE;
    unsigned short* wtv = wtk + WE;
    unsigned short* wto = wtv + WE;
    unsigned short* pq  = wto + WE;
    unsigned short* pk  = pq + WE;
    unsigned short* pv  = pk + WE;
    float* fbias = (float*)(pv + WE);

    const dim3 tgrid(32, 32, 4);
    const dim3 ggrid3(DIMC / 128, NTOK / 128, 3);
    const dim3 ggrid(DIMC / 128, NTOK / 128);
    const dim3 vgrid(SEQ / 64, BATCH * HEADS);
    const dim3 agrid(SEQ / 128, BATCH * HEADS);
    const int eblk = (int)(NE / 256);
    const int wblk = (int)(WE / 256);

    cvt_f32_bf16<<<eblk, 256, 0, stream>>>(x, xb, (int)NE);
    transpose_cvt4<<<tgrid, 256, 0, stream>>>(wq, wk, wv, wo, wtq, wtk, wtv, wto);
    cvt3<<<dim3(wblk, 3), 256, 0, stream>>>(pwq, pwk, pwv, pq, pk, pv);
    maskbias<<<NTOK / 256, 256, 0, stream>>>(mask, fbias);

    // q/k/v = silu(x @ w + b), batched
    gemm_qkv<<<ggrid3, 256, 0, stream>>>(xb, wtq, wtk, wtv, bq, bk, bv, qb, kb, vb);

    // depthwise (batched) -> {xb, tbA, tbB}; pointwise (batched) -> back to q/k/v
    dwconv3<<<dim3(eblk, 3), 256, 0, stream>>>(qb, kb, vb, dwq, dwbq, dwk, dwbk,
                                               dwv, dwbv, xb, tbA, tbB);
    gemm_pw<<<ggrid3, 256, 0, stream>>>(xb, tbA, tbB, pq, pk, pv,
                                        pwbq, pwbk, pwbv, qb, kb, vb);

    // l2 norm (q gets folded softmax scale * log2e)
    l2norm2<<<dim3(NTOK, 2), 256, 0, stream>>>(qb, kb);

    // V transpose, attention (out -> xb), final projection
    vtrans<<<vgrid, 256, 0, stream>>>(vb, vt);
    attn_mfma2<<<agrid, 256, 0, stream>>>(qb, kb, vt, fbias, xb);
    gemm_wo<<<ggrid, 256, 0, stream>>>(xb, wto, bo, out);
}